// Round 11
// baseline (259.733 us; speedup 1.0000x reference)
//
#include <hip/hip_runtime.h>
#include <hip/hip_fp16.h>

#define FD 128    // hidden feature dim
#define OD 64     // output dim
#define RN 256    // nodes per region (id >> 8)
#define CHUNKS 256
#define NRMAX 1024

typedef _Float16 f16x8 __attribute__((ext_vector_type(8)));
typedef float    f32x4 __attribute__((ext_vector_type(4)));
typedef float    f32x2 __attribute__((ext_vector_type(2)));

// ---------------- pass 1: dual histograms by region (dst>>8 and src>>8) ----------------
// hist layout TRANSPOSED: hist_g[region * CHUNKS + chunk] so the scan kernel streams.
// (round-6 lesson: per-edge GLOBAL atomics cost 72us — LDS histograms + spack
// byte scatter is ~3x cheaper. Keep this structure.)

__global__ __launch_bounds__(1024) void region_hist_kernel(const int* __restrict__ src,
                                                           const int* __restrict__ dst,
                                                           int* __restrict__ hist_g,
                                                           int* __restrict__ hist_gs,
                                                           int E, int NR, int CS) {
    __shared__ int hist[NRMAX];
    __shared__ int hist_s[NRMAX];
    int c = blockIdx.x;
    for (int t = threadIdx.x; t < NR; t += 1024) { hist[t] = 0; hist_s[t] = 0; }
    __syncthreads();
    int e0 = c * CS, e1 = min(e0 + CS, E);
    int nv = (e1 - e0) & ~3;
    for (int e = e0 + threadIdx.x * 4; e < e0 + nv; e += 4096) {
        int4 d = *(const int4*)(dst + e);
        int4 s = *(const int4*)(src + e);
        atomicAdd(&hist[d.x >> 8], 1);
        atomicAdd(&hist[d.y >> 8], 1);
        atomicAdd(&hist[d.z >> 8], 1);
        atomicAdd(&hist[d.w >> 8], 1);
        atomicAdd(&hist_s[s.x >> 8], 1);
        atomicAdd(&hist_s[s.y >> 8], 1);
        atomicAdd(&hist_s[s.z >> 8], 1);
        atomicAdd(&hist_s[s.w >> 8], 1);
    }
    for (int e = e0 + nv + threadIdx.x; e < e1; e += 1024) {
        atomicAdd(&hist[dst[e] >> 8], 1);
        atomicAdd(&hist_s[src[e] >> 8], 1);
    }
    __syncthreads();
    for (int t = threadIdx.x; t < NR; t += 1024) {
        hist_g[t * CHUNKS + c]  = hist[t];
        hist_gs[t * CHUNKS + c] = hist_s[t];
    }
}

// ---------------- scan (block 0) + weight fold (blocks 1..16), one launch ----------------
// round-9 lesson: fold in ONE block = 66us latency serialization; spread one
// element per thread. Weights are stored TRANSPOSED ([col][k]) so fused1's MFMA
// B-fragments become contiguous f16x8 vector loads (was 96 scalar 2B loads/thread).
__global__ __launch_bounds__(1024) void scanfold_kernel(const int* __restrict__ hist_g,
                                                        const int* __restrict__ hist_gs,
                                                        int* __restrict__ rstart,
                                                        int* __restrict__ cursor,
                                                        int* __restrict__ sstart,
                                                        int* __restrict__ scursor,
                                                        int NR, int E,
                                                        const float* __restrict__ W2,
                                                        const float* __restrict__ Wf,
                                                        const float* __restrict__ b2,
                                                        const float* __restrict__ bf,
                                                        const float* __restrict__ W1,
                                                        __half* __restrict__ W1t,
                                                        __half* __restrict__ Wct,
                                                        float* __restrict__ bc) {
    __shared__ int wsum[16];
    int tid = threadIdx.x, lane = tid & 63, w = tid >> 6;

    if (blockIdx.x >= 1) {
        // ---- fold, 1 element per thread across 16 blocks; outputs transposed ----
        int gid = (blockIdx.x - 1) * 1024 + tid;   // 0..16383
        if (gid < FD * FD) {
            int col = gid >> 7, k = gid & 127;     // W1t[col][k] = W1[k][col]
            W1t[gid] = __float2half(W1[k * FD + col]);
        }
        if (gid < FD * OD) {
            int col = gid >> 7, k = gid & 127;     // Wct[col][k] = (W2@Wf)[k][col]
            float s = 0.f;
            for (int kk = 0; kk < FD; kk++) s += W2[k * FD + kk] * Wf[kk * OD + col];
            Wct[gid] = __float2half(s);
        }
        if (gid < OD) {
            float s = bf[gid];
            for (int k = 0; k < FD; k++) s += b2[k] * Wf[k * OD + gid];
            bc[gid] = s;
        }
        return;
    }

    // ---- scan 1: dst totals ----
    int total = 0;
    if (tid < NR) {
        const int4* hp = (const int4*)(hist_g + (size_t)tid * CHUNKS);
        #pragma unroll 8
        for (int c4 = 0; c4 < CHUNKS / 4; c4++) {
            int4 h = hp[c4];
            total += h.x + h.y + h.z + h.w;
        }
    }
    int x = total;
    #pragma unroll
    for (int d = 1; d < 64; d <<= 1) {
        int t = __shfl_up(x, d, 64);
        if (lane >= d) x += t;
    }
    if (lane == 63) wsum[w] = x;
    __syncthreads();
    if (w == 0) {
        int s = (lane < 16) ? wsum[lane] : 0;
        #pragma unroll
        for (int d = 1; d < 16; d <<= 1) {
            int t = __shfl_up(s, d, 64);
            if (lane >= d) s += t;
        }
        if (lane < 16) wsum[lane] = s;
    }
    __syncthreads();
    int off = (w == 0) ? 0 : wsum[w - 1];
    if (tid < NR) {
        int start = x + off - total;
        rstart[tid] = start;
        int run = start;
        const int4* hp = (const int4*)(hist_g + (size_t)tid * CHUNKS);
        int4* cp = (int4*)(cursor + (size_t)tid * CHUNKS);
        #pragma unroll 8
        for (int c4 = 0; c4 < CHUNKS / 4; c4++) {
            int4 h = hp[c4];
            int4 o;
            o.x = run; run += h.x;
            o.y = run; run += h.y;
            o.z = run; run += h.z;
            o.w = run; run += h.w;
            cp[c4] = o;
        }
    }
    if (tid == 0) rstart[NR] = E;
    __syncthreads();
    // ---- scan 2: src totals ----
    total = 0;
    if (tid < NR) {
        const int4* hp = (const int4*)(hist_gs + (size_t)tid * CHUNKS);
        #pragma unroll 8
        for (int c4 = 0; c4 < CHUNKS / 4; c4++) {
            int4 h = hp[c4];
            total += h.x + h.y + h.z + h.w;
        }
    }
    x = total;
    #pragma unroll
    for (int d = 1; d < 64; d <<= 1) {
        int t = __shfl_up(x, d, 64);
        if (lane >= d) x += t;
    }
    if (lane == 63) wsum[w] = x;
    __syncthreads();
    if (w == 0) {
        int s = (lane < 16) ? wsum[lane] : 0;
        #pragma unroll
        for (int d = 1; d < 16; d <<= 1) {
            int t = __shfl_up(s, d, 64);
            if (lane >= d) s += t;
        }
        if (lane < 16) wsum[lane] = s;
    }
    __syncthreads();
    off = (w == 0) ? 0 : wsum[w - 1];
    if (tid < NR) {
        int start = x + off - total;
        sstart[tid] = start;
        int run = start;
        const int4* hp = (const int4*)(hist_gs + (size_t)tid * CHUNKS);
        int4* cp = (int4*)(scursor + (size_t)tid * CHUNKS);
        #pragma unroll 8
        for (int c4 = 0; c4 < CHUNKS / 4; c4++) {
            int4 h = hp[c4];
            int4 o;
            o.x = run; run += h.x;
            o.y = run; run += h.y;
            o.z = run; run += h.z;
            o.w = run; run += h.w;
            cp[c4] = o;
        }
    }
    if (tid == 0) sstart[NR] = E;
}

// dual scatter via LDS cursors: epack=((dst&255)<<17|src) by dst-region,
// spack=(src&255) bytes by src-region. NO per-edge global atomics.
__global__ __launch_bounds__(1024) void partition_kernel(const int* __restrict__ src,
                                                         const int* __restrict__ dst,
                                                         const int* __restrict__ cursor,
                                                         const int* __restrict__ scursor,
                                                         int* __restrict__ epack,
                                                         unsigned char* __restrict__ spack,
                                                         int E, int NR, int CS) {
    __shared__ int cur[NRMAX];
    __shared__ int scur[NRMAX];
    int c = blockIdx.x;
    for (int t = threadIdx.x; t < NR; t += 1024) {
        cur[t]  = cursor[(size_t)t * CHUNKS + c];
        scur[t] = scursor[(size_t)t * CHUNKS + c];
    }
    __syncthreads();
    int e0 = c * CS, e1 = min(e0 + CS, E);
    int nv = (e1 - e0) & ~3;
    for (int e = e0 + threadIdx.x * 4; e < e0 + nv; e += 4096) {
        int4 d = *(const int4*)(dst + e);
        int4 s = *(const int4*)(src + e);
        int p0 = atomicAdd(&cur[d.x >> 8], 1);
        int p1 = atomicAdd(&cur[d.y >> 8], 1);
        int p2 = atomicAdd(&cur[d.z >> 8], 1);
        int p3 = atomicAdd(&cur[d.w >> 8], 1);
        epack[p0] = ((d.x & 255) << 17) | s.x;
        epack[p1] = ((d.y & 255) << 17) | s.y;
        epack[p2] = ((d.z & 255) << 17) | s.z;
        epack[p3] = ((d.w & 255) << 17) | s.w;
        int q0 = atomicAdd(&scur[s.x >> 8], 1);
        int q1 = atomicAdd(&scur[s.y >> 8], 1);
        int q2 = atomicAdd(&scur[s.z >> 8], 1);
        int q3 = atomicAdd(&scur[s.w >> 8], 1);
        spack[q0] = (unsigned char)(s.x & 255);
        spack[q1] = (unsigned char)(s.y & 255);
        spack[q2] = (unsigned char)(s.z & 255);
        spack[q3] = (unsigned char)(s.w & 255);
    }
    for (int e = e0 + nv + threadIdx.x; e < e1; e += 1024) {
        int d = dst[e], s = src[e];
        int pos = atomicAdd(&cur[d >> 8], 1);
        epack[pos] = ((d & 255) << 17) | s;
        int qos = atomicAdd(&scur[s >> 8], 1);
        spack[qos] = (unsigned char)(s & 255);
    }
}

// ---------------- region finish: counting sort + src-degree + prescale, one launch ----------------
// block r: (A) dst-region counting sort epack->csrc + row_start + r_in;
//          (B) src-region byte histogram -> r_out for nodes r*RN..r*RN+255;
//          (C) prescale those nodes: Xs = fp16(r_out * in_feat). r_out is
// block-local so no global sync is needed between B and C.
__global__ __launch_bounds__(1024) void region_finish_kernel(const int* __restrict__ epack,
                                                             const int* __restrict__ rstart,
                                                             const unsigned char* __restrict__ spack,
                                                             const int* __restrict__ sstart,
                                                             const float* __restrict__ in_feat,
                                                             int* __restrict__ csrc,
                                                             int* __restrict__ row_start,
                                                             float* __restrict__ r_in,
                                                             float* __restrict__ r_out,
                                                             __half* __restrict__ Xs,
                                                             int N, int NR, int E) {
    __shared__ int cnt[RN];
    __shared__ int cur[RN];
    __shared__ int wsum[16];
    __shared__ float rloc[RN];
    const int r = blockIdx.x, tid = threadIdx.x;
    const int lane = tid & 63, w = tid >> 6;

    // ---- part A: dst-region counting sort ----
    const int s0 = rstart[r], s1 = rstart[r + 1];
    if (tid < RN) cnt[tid] = 0;
    __syncthreads();
    for (int e = s0 + tid; e < s1; e += 1024)
        atomicAdd(&cnt[epack[e] >> 17], 1);
    __syncthreads();
    int cv = (tid < RN) ? cnt[tid] : 0;
    int x = cv;
    #pragma unroll
    for (int d = 1; d < 64; d <<= 1) {
        int t = __shfl_up(x, d, 64);
        if (lane >= d) x += t;
    }
    if (lane == 63 && w < 4) wsum[w] = x;
    __syncthreads();
    if (tid < RN) {
        int woff = 0;
        for (int i = 0; i < w; i++) woff += wsum[i];
        int start = s0 + x - cv + woff;
        cur[tid] = start;
        int node = r * RN + tid;
        if (node < N) {
            row_start[node] = start;
            r_in[node] = rsqrtf((float)max(cv, 1));
        }
    }
    if (r == NR - 1 && tid == 0) row_start[N] = E;
    __syncthreads();
    for (int e = s0 + tid; e < s1; e += 1024) {
        int pk = epack[e];
        int pos = atomicAdd(&cur[pk >> 17], 1);
        csrc[pos] = pk & 0x1FFFF;
    }
    __syncthreads();

    // ---- part B: src-region byte histogram -> r_out ----
    const int t0 = sstart[r], t1 = sstart[r + 1];
    if (tid < RN) cnt[tid] = 0;
    __syncthreads();
    for (int e = t0 + tid; e < t1; e += 1024)
        atomicAdd(&cnt[spack[e]], 1);
    __syncthreads();
    if (tid < RN) {
        float ro = rsqrtf((float)max(cnt[tid], 1));
        rloc[tid] = ro;
        int node = r * RN + tid;
        if (node < N) r_out[node] = ro;
    }
    __syncthreads();

    // ---- part C: prescale own 256 nodes (32 float4 per row) ----
    for (int idx = tid; idx < RN * 32; idx += 1024) {
        int nrow = idx >> 5;
        int node = r * RN + nrow;
        if (node >= N) break;
        int gi = node * 32 + (idx & 31);
        float ro = rloc[nrow];
        float4 t = ((const float4*)in_feat)[gi];
        ((__half2*)Xs)[2 * gi]     = __floats2half2_rn(t.x * ro, t.y * ro);
        ((__half2*)Xs)[2 * gi + 1] = __floats2half2_rn(t.z * ro, t.w * ro);
    }
}

// ---------------- fused layer-1: aggregate 16 nodes -> LDS tile -> GEMM1 -> GEMM2 ----------------
// block = 4 waves = 16 nodes. Round-11: B fragments loaded BEFORE phase A (latency
// hidden under the gather) as contiguous f16x8 vectors from transposed weights
// (was 96 scalar 2B loads/thread after the barrier).
__global__ __launch_bounds__(256) void fused1_kernel(const __half* __restrict__ Xs,
                                                     const float* __restrict__ r_in,
                                                     const float* __restrict__ r_out,
                                                     const int* __restrict__ rs,
                                                     const int* __restrict__ csrc,
                                                     const __half* __restrict__ W1t,
                                                     const float* __restrict__ b1,
                                                     const __half* __restrict__ Wct,
                                                     __half* __restrict__ tbuf,
                                                     int N) {
    const int tid = threadIdx.x;
    const int lane = tid & 63, w = tid >> 6;
    const int l15 = lane & 15, quad = lane >> 4;
    const int base = blockIdx.x * 16;
    __shared__ __half2  zt[16][68];    // z1 tile, row stride 272B (2-way LDS aliasing only)
    __shared__ _Float16 yt[16][136];   // y1 tile, same stride

    // ---- B fragments: contiguous vector loads, issued up-front (hide under gather) ----
    const int col2 = 16 * w + l15;
    f16x8 bf1[2][4];
    #pragma unroll
    for (int nt = 0; nt < 2; nt++) {
        int col = 32 * w + 16 * nt + l15;
        const f16x8* bp = (const f16x8*)((const _Float16*)W1t + (size_t)col * FD + quad * 8);
        #pragma unroll
        for (int kk = 0; kk < 4; kk++) bf1[nt][kk] = bp[kk * 4];
    }
    f16x8 bf2[4];
    {
        const f16x8* bp = (const f16x8*)((const _Float16*)Wct + (size_t)col2 * FD + quad * 8);
        #pragma unroll
        for (int kk = 0; kk < 4; kk++) bf2[kk] = bp[kk * 4];
    }

    // ---- phase A: each wave aggregates 4 nodes (rows w, 4+w, 8+w, 12+w) ----
    for (int j = 0; j < 4; j++) {
        const int row = 4 * j + w;
        const int v = base + row;
        float ax = 0.f, ay = 0.f;
        if (v < N) {
            int s0 = __builtin_amdgcn_readfirstlane(rs[v]);
            int s1 = __builtin_amdgcn_readfirstlane(rs[v + 1]);
            const int deg = s1 - s0;
            const int nb = deg >> 4;
            int e = s0;
            if (nb) {
                int ia[16];
                #pragma unroll
                for (int u = 0; u < 16; u++) ia[u] = csrc[e + u];
                for (int b = 1; b < nb; b++) {
                    __half2 t[16];
                    #pragma unroll
                    for (int u = 0; u < 16; u++)
                        t[u] = ((const __half2*)(Xs + (size_t)ia[u] * FD))[lane];
                    int eb = e + (b << 4);
                    #pragma unroll
                    for (int u = 0; u < 16; u++) ia[u] = csrc[eb + u];
                    #pragma unroll
                    for (int u = 0; u < 16; u++) {
                        float2 f = __half22float2(t[u]);
                        ax += f.x; ay += f.y;
                    }
                }
                __half2 t[16];
                #pragma unroll
                for (int u = 0; u < 16; u++)
                    t[u] = ((const __half2*)(Xs + (size_t)ia[u] * FD))[lane];
                #pragma unroll
                for (int u = 0; u < 16; u++) {
                    float2 f = __half22float2(t[u]);
                    ax += f.x; ay += f.y;
                }
                e += nb << 4;
            }
            const int rem = s1 - e;          // 0..15, wave-uniform
            if (rem) {
                const int last = s1 - 1;
                int ia[16];
                #pragma unroll
                for (int u = 0; u < 16; u++) ia[u] = csrc[min(e + u, last)];
                #pragma unroll
                for (int u = 0; u < 16; u++) {
                    unsigned raw = ((const unsigned*)(Xs + (size_t)ia[u] * FD))[lane];
                    raw = (u < rem) ? raw : 0u;
                    union { unsigned q; __half2 h; } tt; tt.q = raw;
                    float2 f = __half22float2(tt.h);
                    ax += f.x; ay += f.y;
                }
            }
            float ri = r_in[v];
            zt[row][lane] = __floats2half2_rn(ax * ri, ay * ri);
        } else {
            zt[row][lane] = __floats2half2_rn(0.f, 0.f);
        }
    }
    __syncthreads();

    // ---- phase B: GEMM1 (z @ W1 + b1, relu, * r_out) -> yt ----
    {
        const _Float16* Arow = (const _Float16*)&zt[l15][0] + quad * 8;
        f16x8 afrag[4];
        #pragma unroll
        for (int kk = 0; kk < 4; kk++) afrag[kk] = *(const f16x8*)(Arow + kk * 32);
        f32x4 acc0 = {0.f, 0.f, 0.f, 0.f};
        f32x4 acc1 = {0.f, 0.f, 0.f, 0.f};
        #pragma unroll
        for (int kk = 0; kk < 4; kk++) {
            acc0 = __builtin_amdgcn_mfma_f32_16x16x32_f16(afrag[kk], bf1[0][kk], acc0, 0, 0, 0);
            acc1 = __builtin_amdgcn_mfma_f32_16x16x32_f16(afrag[kk], bf1[1][kk], acc1, 0, 0, 0);
        }
        int c0 = 32 * w + l15, c1 = c0 + 16;
        float bb0 = b1[c0], bb1 = b1[c1];
        #pragma unroll
        for (int r = 0; r < 4; r++) {
            int row = quad * 4 + r;
            int v = base + row;
            float rsc = (v < N) ? r_out[v] : 0.f;
            yt[row][c0] = (_Float16)(fmaxf(acc0[r] + bb0, 0.f) * rsc);
            yt[row][c1] = (_Float16)(fmaxf(acc1[r] + bb1, 0.f) * rsc);
        }
    }
    __syncthreads();

    // ---- phase C: GEMM2 (y @ Wc) -> tbuf ----
    {
        const _Float16* Arow = &yt[l15][0] + quad * 8;
        f16x8 afrag[4];
        #pragma unroll
        for (int kk = 0; kk < 4; kk++) afrag[kk] = *(const f16x8*)(Arow + kk * 32);
        f32x4 acc = {0.f, 0.f, 0.f, 0.f};
        #pragma unroll
        for (int kk = 0; kk < 4; kk++)
            acc = __builtin_amdgcn_mfma_f32_16x16x32_f16(afrag[kk], bf2[kk], acc, 0, 0, 0);
        #pragma unroll
        for (int r = 0; r < 4; r++) {
            int row = quad * 4 + r;
            int v = base + row;
            if (v < N)
                tbuf[(size_t)v * OD + col2] = __float2half(acc[r]);
        }
    }
}

// ---------------- final aggregation: 2 nodes per wave, pipelined ----------------
__global__ __launch_bounds__(256) void agg64_kernel(const __half* __restrict__ T,
                                                    const float* __restrict__ r_in,
                                                    const int* __restrict__ rs,
                                                    const int* __restrict__ csrc,
                                                    const float* __restrict__ bc,
                                                    float* __restrict__ out, int N) {
    const int tid = threadIdx.x;
    const int lane = tid & 63, wv = tid >> 6;
    const int hf = lane >> 5, l32 = lane & 31;
    int v = blockIdx.x * 8 + wv * 2 + hf;
    if (v >= N) return;
    int s0 = rs[v], s1 = rs[v + 1];          // half-wave uniform
    const int deg = s1 - s0;
    float ax = 0.f, ay = 0.f;
    const int nb = deg >> 3;
    int e = s0;
    if (nb) {
        int ia[8];
        #pragma unroll
        for (int u = 0; u < 8; u++) ia[u] = csrc[e + u];
        for (int b = 1; b < nb; b++) {
            __half2 t[8];
            #pragma unroll
            for (int u = 0; u < 8; u++)
                t[u] = ((const __half2*)(T + (size_t)ia[u] * OD))[l32];
            int eb = e + (b << 3);
            #pragma unroll
            for (int u = 0; u < 8; u++) ia[u] = csrc[eb + u];
            #pragma unroll
            for (int u = 0; u < 8; u++) {
                float2 f = __half22float2(t[u]);
                ax += f.x; ay += f.y;
            }
        }
        __half2 t[8];
        #pragma unroll
        for (int u = 0; u < 8; u++)
            t[u] = ((const __half2*)(T + (size_t)ia[u] * OD))[l32];
        #pragma unroll
        for (int u = 0; u < 8; u++) {
            float2 f = __half22float2(t[u]);
            ax += f.x; ay += f.y;
        }
        e += nb << 3;
    }
    const int rem = s1 - e;                  // 0..7 (per half-wave)
    if (rem) {
        const int last = s1 - 1;
        int ia[8];
        #pragma unroll
        for (int u = 0; u < 8; u++) ia[u] = csrc[min(e + u, last)];
        #pragma unroll
        for (int u = 0; u < 8; u++) {
            unsigned raw = ((const unsigned*)(T + (size_t)ia[u] * OD))[l32];
            raw = (u < rem) ? raw : 0u;
            union { unsigned q; __half2 h; } tt; tt.q = raw;
            float2 f = __half22float2(tt.h);
            ax += f.x; ay += f.y;
        }
    }
    float ri = r_in[v];
    f32x2 o;
    o.x = ax * ri + bc[l32 * 2];
    o.y = ay * ri + bc[l32 * 2 + 1];
    __builtin_nontemporal_store(o, (f32x2*)(out + (size_t)v * OD) + l32);
}

// ---------------- launch ----------------
extern "C" void kernel_launch(void* const* d_in, const int* in_sizes, int n_in,
                              void* d_out, int out_size, void* d_ws, size_t ws_size,
                              hipStream_t stream) {
    const float* in_feat = (const float*)d_in[0];
    const int*   src     = (const int*)d_in[1];
    const int*   dst     = (const int*)d_in[2];
    const float* W1      = (const float*)d_in[3];
    const float* b1      = (const float*)d_in[4];
    const float* W2      = (const float*)d_in[5];
    const float* b2      = (const float*)d_in[6];
    const float* Wf      = (const float*)d_in[7];
    const float* bf      = (const float*)d_in[8];
    float* out = (float*)d_out;

    const int N = in_sizes[0] / FD;        // 50000
    const int E = in_sizes[1];             // 1600000
    const int NR = (N + RN - 1) / RN;      // 196 (<= NRMAX)
    const int CS = (((E + CHUNKS - 1) / CHUNKS) + 3) & ~3;  // 4-aligned for int4

    char* ws = (char*)d_ws;
    size_t off = 0;
    auto alloc = [&](size_t bytes) -> void* {
        void* p = ws + off;
        off += (bytes + 255) / 256 * 256;
        return p;
    };
    // spack (1.6 MB) + epack (6.4 MB) adjacent; both dead before fused1 writes
    // tbuf (N*OD*2 = 6.4 MB) which aliases them.
    unsigned char* spack = (unsigned char*)alloc((size_t)E);
    int*    epack   = (int*)alloc((size_t)E * 4);
    __half* tbuf    = (__half*)spack;              // row-major [N][64]
    float*  r_out   = (float*)alloc((size_t)N * 4);
    float*  r_in    = (float*)alloc((size_t)N * 4);
    int*    hist_g  = (int*)alloc((size_t)CHUNKS * NRMAX * 4);
    int*    hist_gs = (int*)alloc((size_t)CHUNKS * NRMAX * 4);
    int*    cursor  = (int*)alloc((size_t)CHUNKS * NRMAX * 4);
    int*    scursor = (int*)alloc((size_t)CHUNKS * NRMAX * 4);
    int*    rstart  = (int*)alloc((size_t)(NR + 1) * 4);
    int*    sstart  = (int*)alloc((size_t)(NR + 1) * 4);
    int*    csrc    = (int*)alloc((size_t)E * 4);
    int*    row_start = (int*)alloc((size_t)(N + 1) * 4);
    __half* Xs      = (__half*)alloc((size_t)N * FD * 2);   // row-major [N][128]
    __half* W1t     = (__half*)alloc((size_t)FD * FD * 2);  // transposed [col][k]
    __half* Wct     = (__half*)alloc((size_t)OD * FD * 2);  // transposed [col][k]
    float*  bc      = (float*)alloc((size_t)OD * 4);
    (void)ws_size; (void)n_in; (void)out_size;

    // 6 launches total; fold spread over 16 blocks inside the scan launch.
    region_hist_kernel<<<CHUNKS, 1024, 0, stream>>>(src, dst, hist_g, hist_gs, E, NR, CS);
    scanfold_kernel<<<17, 1024, 0, stream>>>(hist_g, hist_gs, rstart, cursor, sstart, scursor,
                                             NR, E, W2, Wf, b2, bf, W1, W1t, Wct, bc);
    partition_kernel<<<CHUNKS, 1024, 0, stream>>>(src, dst, cursor, scursor, epack, spack, E, NR, CS);
    region_finish_kernel<<<NR, 1024, 0, stream>>>(epack, rstart, spack, sstart, in_feat,
                                                  csrc, row_start, r_in, r_out, Xs, N, NR, E);
    fused1_kernel<<<(N + 15) / 16, 256, 0, stream>>>(Xs, r_in, r_out, row_start, csrc,
                                                     W1t, b1, Wct, tbuf, N);
    agg64_kernel<<<(N + 7) / 8, 256, 0, stream>>>(tbuf, r_in, row_start, csrc, bc, out, N);
}

// Round 12
// 257.502 us; speedup vs baseline: 1.0087x; 1.0087x over previous
//
#include <hip/hip_runtime.h>
#include <hip/hip_fp16.h>

#define FD 128    // hidden feature dim
#define OD 64     // output dim
#define RN 256    // nodes per region (id >> 8)
#define CHUNKS 256
#define NRMAX 1024

typedef _Float16 f16x8 __attribute__((ext_vector_type(8)));
typedef float    f32x4 __attribute__((ext_vector_type(4)));
typedef float    f32x2 __attribute__((ext_vector_type(2)));

// ---------------- pass 1: dual histograms by region (dst>>8 and src>>8) ----------------
// hist layout TRANSPOSED: hist_g[region * CHUNKS + chunk] so the scan kernel streams.
// (round-6 lesson: per-edge GLOBAL atomics cost 72us — LDS histograms + spack
// byte scatter is ~3x cheaper. Keep this structure.)

__global__ __launch_bounds__(1024) void region_hist_kernel(const int* __restrict__ src,
                                                           const int* __restrict__ dst,
                                                           int* __restrict__ hist_g,
                                                           int* __restrict__ hist_gs,
                                                           int E, int NR, int CS) {
    __shared__ int hist[NRMAX];
    __shared__ int hist_s[NRMAX];
    int c = blockIdx.x;
    for (int t = threadIdx.x; t < NR; t += 1024) { hist[t] = 0; hist_s[t] = 0; }
    __syncthreads();
    int e0 = c * CS, e1 = min(e0 + CS, E);
    int nv = (e1 - e0) & ~3;
    for (int e = e0 + threadIdx.x * 4; e < e0 + nv; e += 4096) {
        int4 d = *(const int4*)(dst + e);
        int4 s = *(const int4*)(src + e);
        atomicAdd(&hist[d.x >> 8], 1);
        atomicAdd(&hist[d.y >> 8], 1);
        atomicAdd(&hist[d.z >> 8], 1);
        atomicAdd(&hist[d.w >> 8], 1);
        atomicAdd(&hist_s[s.x >> 8], 1);
        atomicAdd(&hist_s[s.y >> 8], 1);
        atomicAdd(&hist_s[s.z >> 8], 1);
        atomicAdd(&hist_s[s.w >> 8], 1);
    }
    for (int e = e0 + nv + threadIdx.x; e < e1; e += 1024) {
        atomicAdd(&hist[dst[e] >> 8], 1);
        atomicAdd(&hist_s[src[e] >> 8], 1);
    }
    __syncthreads();
    for (int t = threadIdx.x; t < NR; t += 1024) {
        hist_g[t * CHUNKS + c]  = hist[t];
        hist_gs[t * CHUNKS + c] = hist_s[t];
    }
}

// ---------------- scan (block 0) + weight fold (blocks 1..16), one launch ----------------
// round-9 lesson: fold in ONE block = 66us latency serialization; spread one
// element per thread. Weights stored TRANSPOSED ([col][k]) so fused1's MFMA
// B-fragments are contiguous f16x8 vector loads.
__global__ __launch_bounds__(1024) void scanfold_kernel(const int* __restrict__ hist_g,
                                                        const int* __restrict__ hist_gs,
                                                        int* __restrict__ rstart,
                                                        int* __restrict__ cursor,
                                                        int* __restrict__ sstart,
                                                        int* __restrict__ scursor,
                                                        int NR, int E,
                                                        const float* __restrict__ W2,
                                                        const float* __restrict__ Wf,
                                                        const float* __restrict__ b2,
                                                        const float* __restrict__ bf,
                                                        const float* __restrict__ W1,
                                                        __half* __restrict__ W1t,
                                                        __half* __restrict__ Wct,
                                                        float* __restrict__ bc) {
    __shared__ int wsum[16];
    int tid = threadIdx.x, lane = tid & 63, w = tid >> 6;

    if (blockIdx.x >= 1) {
        // ---- fold, 1 element per thread across 16 blocks; outputs transposed ----
        int gid = (blockIdx.x - 1) * 1024 + tid;   // 0..16383
        if (gid < FD * FD) {
            int col = gid >> 7, k = gid & 127;     // W1t[col][k] = W1[k][col]
            W1t[gid] = __float2half(W1[k * FD + col]);
        }
        if (gid < FD * OD) {
            int col = gid >> 7, k = gid & 127;     // Wct[col][k] = (W2@Wf)[k][col]
            float s = 0.f;
            for (int kk = 0; kk < FD; kk++) s += W2[k * FD + kk] * Wf[kk * OD + col];
            Wct[gid] = __float2half(s);
        }
        if (gid < OD) {
            float s = bf[gid];
            for (int k = 0; k < FD; k++) s += b2[k] * Wf[k * OD + gid];
            bc[gid] = s;
        }
        return;
    }

    // ---- scan 1: dst totals ----
    int total = 0;
    if (tid < NR) {
        const int4* hp = (const int4*)(hist_g + (size_t)tid * CHUNKS);
        #pragma unroll 8
        for (int c4 = 0; c4 < CHUNKS / 4; c4++) {
            int4 h = hp[c4];
            total += h.x + h.y + h.z + h.w;
        }
    }
    int x = total;
    #pragma unroll
    for (int d = 1; d < 64; d <<= 1) {
        int t = __shfl_up(x, d, 64);
        if (lane >= d) x += t;
    }
    if (lane == 63) wsum[w] = x;
    __syncthreads();
    if (w == 0) {
        int s = (lane < 16) ? wsum[lane] : 0;
        #pragma unroll
        for (int d = 1; d < 16; d <<= 1) {
            int t = __shfl_up(s, d, 64);
            if (lane >= d) s += t;
        }
        if (lane < 16) wsum[lane] = s;
    }
    __syncthreads();
    int off = (w == 0) ? 0 : wsum[w - 1];
    if (tid < NR) {
        int start = x + off - total;
        rstart[tid] = start;
        int run = start;
        const int4* hp = (const int4*)(hist_g + (size_t)tid * CHUNKS);
        int4* cp = (int4*)(cursor + (size_t)tid * CHUNKS);
        #pragma unroll 8
        for (int c4 = 0; c4 < CHUNKS / 4; c4++) {
            int4 h = hp[c4];
            int4 o;
            o.x = run; run += h.x;
            o.y = run; run += h.y;
            o.z = run; run += h.z;
            o.w = run; run += h.w;
            cp[c4] = o;
        }
    }
    if (tid == 0) rstart[NR] = E;
    __syncthreads();
    // ---- scan 2: src totals ----
    total = 0;
    if (tid < NR) {
        const int4* hp = (const int4*)(hist_gs + (size_t)tid * CHUNKS);
        #pragma unroll 8
        for (int c4 = 0; c4 < CHUNKS / 4; c4++) {
            int4 h = hp[c4];
            total += h.x + h.y + h.z + h.w;
        }
    }
    x = total;
    #pragma unroll
    for (int d = 1; d < 64; d <<= 1) {
        int t = __shfl_up(x, d, 64);
        if (lane >= d) x += t;
    }
    if (lane == 63) wsum[w] = x;
    __syncthreads();
    if (w == 0) {
        int s = (lane < 16) ? wsum[lane] : 0;
        #pragma unroll
        for (int d = 1; d < 16; d <<= 1) {
            int t = __shfl_up(s, d, 64);
            if (lane >= d) s += t;
        }
        if (lane < 16) wsum[lane] = s;
    }
    __syncthreads();
    off = (w == 0) ? 0 : wsum[w - 1];
    if (tid < NR) {
        int start = x + off - total;
        sstart[tid] = start;
        int run = start;
        const int4* hp = (const int4*)(hist_gs + (size_t)tid * CHUNKS);
        int4* cp = (int4*)(scursor + (size_t)tid * CHUNKS);
        #pragma unroll 8
        for (int c4 = 0; c4 < CHUNKS / 4; c4++) {
            int4 h = hp[c4];
            int4 o;
            o.x = run; run += h.x;
            o.y = run; run += h.y;
            o.z = run; run += h.z;
            o.w = run; run += h.w;
            cp[c4] = o;
        }
    }
    if (tid == 0) sstart[NR] = E;
}

// dual scatter via LDS cursors: epack=((dst&255)<<17|src) by dst-region,
// spack=(src&255) bytes by src-region. NO per-edge global atomics.
__global__ __launch_bounds__(1024) void partition_kernel(const int* __restrict__ src,
                                                         const int* __restrict__ dst,
                                                         const int* __restrict__ cursor,
                                                         const int* __restrict__ scursor,
                                                         int* __restrict__ epack,
                                                         unsigned char* __restrict__ spack,
                                                         int E, int NR, int CS) {
    __shared__ int cur[NRMAX];
    __shared__ int scur[NRMAX];
    int c = blockIdx.x;
    for (int t = threadIdx.x; t < NR; t += 1024) {
        cur[t]  = cursor[(size_t)t * CHUNKS + c];
        scur[t] = scursor[(size_t)t * CHUNKS + c];
    }
    __syncthreads();
    int e0 = c * CS, e1 = min(e0 + CS, E);
    int nv = (e1 - e0) & ~3;
    for (int e = e0 + threadIdx.x * 4; e < e0 + nv; e += 4096) {
        int4 d = *(const int4*)(dst + e);
        int4 s = *(const int4*)(src + e);
        int p0 = atomicAdd(&cur[d.x >> 8], 1);
        int p1 = atomicAdd(&cur[d.y >> 8], 1);
        int p2 = atomicAdd(&cur[d.z >> 8], 1);
        int p3 = atomicAdd(&cur[d.w >> 8], 1);
        epack[p0] = ((d.x & 255) << 17) | s.x;
        epack[p1] = ((d.y & 255) << 17) | s.y;
        epack[p2] = ((d.z & 255) << 17) | s.z;
        epack[p3] = ((d.w & 255) << 17) | s.w;
        int q0 = atomicAdd(&scur[s.x >> 8], 1);
        int q1 = atomicAdd(&scur[s.y >> 8], 1);
        int q2 = atomicAdd(&scur[s.z >> 8], 1);
        int q3 = atomicAdd(&scur[s.w >> 8], 1);
        spack[q0] = (unsigned char)(s.x & 255);
        spack[q1] = (unsigned char)(s.y & 255);
        spack[q2] = (unsigned char)(s.z & 255);
        spack[q3] = (unsigned char)(s.w & 255);
    }
    for (int e = e0 + nv + threadIdx.x; e < e1; e += 1024) {
        int d = dst[e], s = src[e];
        int pos = atomicAdd(&cur[d >> 8], 1);
        epack[pos] = ((d & 255) << 17) | s;
        int qos = atomicAdd(&scur[s >> 8], 1);
        spack[qos] = (unsigned char)(s & 255);
    }
}

// ---------------- region finish: counting sort + src-degree + prescale, one launch ----------------
// block r: (A) dst-region counting sort epack->csrc + row_start + r_in;
//          (B) src-region byte histogram -> r_out for nodes r*RN..r*RN+255;
//          (C) prescale those nodes: Xs = fp16(r_out * in_feat). r_out is
// block-local so no global sync is needed between B and C.
__global__ __launch_bounds__(1024) void region_finish_kernel(const int* __restrict__ epack,
                                                             const int* __restrict__ rstart,
                                                             const unsigned char* __restrict__ spack,
                                                             const int* __restrict__ sstart,
                                                             const float* __restrict__ in_feat,
                                                             int* __restrict__ csrc,
                                                             int* __restrict__ row_start,
                                                             float* __restrict__ r_in,
                                                             float* __restrict__ r_out,
                                                             __half* __restrict__ Xs,
                                                             int N, int NR, int E) {
    __shared__ int cnt[RN];
    __shared__ int cur[RN];
    __shared__ int wsum[16];
    __shared__ float rloc[RN];
    const int r = blockIdx.x, tid = threadIdx.x;
    const int lane = tid & 63, w = tid >> 6;

    // ---- part A: dst-region counting sort ----
    const int s0 = rstart[r], s1 = rstart[r + 1];
    if (tid < RN) cnt[tid] = 0;
    __syncthreads();
    for (int e = s0 + tid; e < s1; e += 1024)
        atomicAdd(&cnt[epack[e] >> 17], 1);
    __syncthreads();
    int cv = (tid < RN) ? cnt[tid] : 0;
    int x = cv;
    #pragma unroll
    for (int d = 1; d < 64; d <<= 1) {
        int t = __shfl_up(x, d, 64);
        if (lane >= d) x += t;
    }
    if (lane == 63 && w < 4) wsum[w] = x;
    __syncthreads();
    if (tid < RN) {
        int woff = 0;
        for (int i = 0; i < w; i++) woff += wsum[i];
        int start = s0 + x - cv + woff;
        cur[tid] = start;
        int node = r * RN + tid;
        if (node < N) {
            row_start[node] = start;
            r_in[node] = rsqrtf((float)max(cv, 1));
        }
    }
    if (r == NR - 1 && tid == 0) row_start[N] = E;
    __syncthreads();
    for (int e = s0 + tid; e < s1; e += 1024) {
        int pk = epack[e];
        int pos = atomicAdd(&cur[pk >> 17], 1);
        csrc[pos] = pk & 0x1FFFF;
    }
    __syncthreads();

    // ---- part B: src-region byte histogram -> r_out ----
    const int t0 = sstart[r], t1 = sstart[r + 1];
    if (tid < RN) cnt[tid] = 0;
    __syncthreads();
    for (int e = t0 + tid; e < t1; e += 1024)
        atomicAdd(&cnt[spack[e]], 1);
    __syncthreads();
    if (tid < RN) {
        float ro = rsqrtf((float)max(cnt[tid], 1));
        rloc[tid] = ro;
        int node = r * RN + tid;
        if (node < N) r_out[node] = ro;
    }
    __syncthreads();

    // ---- part C: prescale own 256 nodes (32 float4 per row) ----
    for (int idx = tid; idx < RN * 32; idx += 1024) {
        int nrow = idx >> 5;
        int node = r * RN + nrow;
        if (node >= N) break;
        int gi = node * 32 + (idx & 31);
        float ro = rloc[nrow];
        float4 t = ((const float4*)in_feat)[gi];
        ((__half2*)Xs)[2 * gi]     = __floats2half2_rn(t.x * ro, t.y * ro);
        ((__half2*)Xs)[2 * gi + 1] = __floats2half2_rn(t.z * ro, t.w * ro);
    }
}

// ---------------- fused layer-1 v2: 16 waves, ONE NODE PER WAVE ----------------
// round-11 diagnosis: 4-wave fused1 had 12.5k waves (4 sequential nodes/wave) vs
// standalone agg128's 50k waves (1 node/wave) -> 1/4 the outstanding gathers ->
// 2.3 vs 3.65 TB/s service. This version: block = 1024 thr = 16 waves, wave w
// aggregates node base+w exactly like the proven agg128 loop; then waves 0..7
// do GEMM1 (one 16-col tile each), waves 0..3 do GEMM2. launch_bounds(1024,8)
// keeps VGPR<=64 so 2 blocks/CU (32 waves) fit.
__global__ __launch_bounds__(1024, 8) void fused1_kernel(const __half* __restrict__ Xs,
                                                         const float* __restrict__ r_in,
                                                         const float* __restrict__ r_out,
                                                         const int* __restrict__ rs,
                                                         const int* __restrict__ csrc,
                                                         const __half* __restrict__ W1t,
                                                         const float* __restrict__ b1,
                                                         const __half* __restrict__ Wct,
                                                         __half* __restrict__ tbuf,
                                                         int N) {
    const int tid = threadIdx.x;
    const int lane = tid & 63, w = tid >> 6;      // 16 waves
    const int l15 = lane & 15, quad = lane >> 4;
    const int base = blockIdx.x * 16;
    __shared__ __half2  zt[16][68];    // z1 tile, row stride 272B (2-way LDS aliasing only)
    __shared__ _Float16 yt[16][136];   // y1 tile, same stride

    // ---- phase A: wave w aggregates node base+w (full 128-feature row) ----
    {
        const int v = base + w;
        float ax = 0.f, ay = 0.f;
        if (v < N) {
            int s0 = __builtin_amdgcn_readfirstlane(rs[v]);
            int s1 = __builtin_amdgcn_readfirstlane(rs[v + 1]);
            const int deg = s1 - s0;
            const int nb = deg >> 4;
            int e = s0;
            if (nb) {
                int ia[16];
                #pragma unroll
                for (int u = 0; u < 16; u++) ia[u] = csrc[e + u];
                for (int b = 1; b < nb; b++) {
                    __half2 t[16];
                    #pragma unroll
                    for (int u = 0; u < 16; u++)
                        t[u] = ((const __half2*)(Xs + (size_t)ia[u] * FD))[lane];
                    int eb = e + (b << 4);
                    #pragma unroll
                    for (int u = 0; u < 16; u++) ia[u] = csrc[eb + u];
                    #pragma unroll
                    for (int u = 0; u < 16; u++) {
                        float2 f = __half22float2(t[u]);
                        ax += f.x; ay += f.y;
                    }
                }
                __half2 t[16];
                #pragma unroll
                for (int u = 0; u < 16; u++)
                    t[u] = ((const __half2*)(Xs + (size_t)ia[u] * FD))[lane];
                #pragma unroll
                for (int u = 0; u < 16; u++) {
                    float2 f = __half22float2(t[u]);
                    ax += f.x; ay += f.y;
                }
                e += nb << 4;
            }
            const int rem = s1 - e;          // 0..15, wave-uniform
            if (rem) {
                const int last = s1 - 1;
                int ia[16];
                #pragma unroll
                for (int u = 0; u < 16; u++) ia[u] = csrc[min(e + u, last)];
                #pragma unroll
                for (int u = 0; u < 16; u++) {
                    unsigned raw = ((const unsigned*)(Xs + (size_t)ia[u] * FD))[lane];
                    raw = (u < rem) ? raw : 0u;
                    union { unsigned q; __half2 h; } tt; tt.q = raw;
                    float2 f = __half22float2(tt.h);
                    ax += f.x; ay += f.y;
                }
            }
            float ri = r_in[v];
            zt[w][lane] = __floats2half2_rn(ax * ri, ay * ri);
        } else {
            zt[w][lane] = __floats2half2_rn(0.f, 0.f);
        }
    }
    __syncthreads();

    // ---- phase B: GEMM1 (z @ W1 + b1, relu, * r_out) -> yt ; waves 0..7, 16 cols each ----
    if (w < 8) {
        const int col = 16 * w + l15;
        const f16x8* bp = (const f16x8*)((const _Float16*)W1t + (size_t)col * FD + quad * 8);
        f16x8 bf[4];
        #pragma unroll
        for (int kk = 0; kk < 4; kk++) bf[kk] = bp[kk * 4];
        const _Float16* Arow = (const _Float16*)&zt[l15][0] + quad * 8;
        f16x8 afrag[4];
        #pragma unroll
        for (int kk = 0; kk < 4; kk++) afrag[kk] = *(const f16x8*)(Arow + kk * 32);
        f32x4 acc = {0.f, 0.f, 0.f, 0.f};
        #pragma unroll
        for (int kk = 0; kk < 4; kk++)
            acc = __builtin_amdgcn_mfma_f32_16x16x32_f16(afrag[kk], bf[kk], acc, 0, 0, 0);
        float bb = b1[col];
        #pragma unroll
        for (int r = 0; r < 4; r++) {
            int row = quad * 4 + r;
            int v = base + row;
            float rsc = (v < N) ? r_out[v] : 0.f;
            yt[row][col] = (_Float16)(fmaxf(acc[r] + bb, 0.f) * rsc);
        }
    }
    __syncthreads();

    // ---- phase C: GEMM2 (y @ Wc) -> tbuf ; waves 0..3, 16 cols each ----
    if (w < 4) {
        const int col = 16 * w + l15;
        const f16x8* bp = (const f16x8*)((const _Float16*)Wct + (size_t)col * FD + quad * 8);
        f16x8 bf[4];
        #pragma unroll
        for (int kk = 0; kk < 4; kk++) bf[kk] = bp[kk * 4];
        const _Float16* Arow = &yt[l15][0] + quad * 8;
        f16x8 afrag[4];
        #pragma unroll
        for (int kk = 0; kk < 4; kk++) afrag[kk] = *(const f16x8*)(Arow + kk * 32);
        f32x4 acc = {0.f, 0.f, 0.f, 0.f};
        #pragma unroll
        for (int kk = 0; kk < 4; kk++)
            acc = __builtin_amdgcn_mfma_f32_16x16x32_f16(afrag[kk], bf[kk], acc, 0, 0, 0);
        #pragma unroll
        for (int r = 0; r < 4; r++) {
            int row = quad * 4 + r;
            int v = base + row;
            if (v < N)
                tbuf[(size_t)v * OD + col] = __float2half(acc[r]);
        }
    }
}

// ---------------- final aggregation: 2 nodes per wave, pipelined ----------------
__global__ __launch_bounds__(256) void agg64_kernel(const __half* __restrict__ T,
                                                    const float* __restrict__ r_in,
                                                    const int* __restrict__ rs,
                                                    const int* __restrict__ csrc,
                                                    const float* __restrict__ bc,
                                                    float* __restrict__ out, int N) {
    const int tid = threadIdx.x;
    const int lane = tid & 63, wv = tid >> 6;
    const int hf = lane >> 5, l32 = lane & 31;
    int v = blockIdx.x * 8 + wv * 2 + hf;
    if (v >= N) return;
    int s0 = rs[v], s1 = rs[v + 1];          // half-wave uniform
    const int deg = s1 - s0;
    float ax = 0.f, ay = 0.f;
    const int nb = deg >> 3;
    int e = s0;
    if (nb) {
        int ia[8];
        #pragma unroll
        for (int u = 0; u < 8; u++) ia[u] = csrc[e + u];
        for (int b = 1; b < nb; b++) {
            __half2 t[8];
            #pragma unroll
            for (int u = 0; u < 8; u++)
                t[u] = ((const __half2*)(T + (size_t)ia[u] * OD))[l32];
            int eb = e + (b << 3);
            #pragma unroll
            for (int u = 0; u < 8; u++) ia[u] = csrc[eb + u];
            #pragma unroll
            for (int u = 0; u < 8; u++) {
                float2 f = __half22float2(t[u]);
                ax += f.x; ay += f.y;
            }
        }
        __half2 t[8];
        #pragma unroll
        for (int u = 0; u < 8; u++)
            t[u] = ((const __half2*)(T + (size_t)ia[u] * OD))[l32];
        #pragma unroll
        for (int u = 0; u < 8; u++) {
            float2 f = __half22float2(t[u]);
            ax += f.x; ay += f.y;
        }
        e += nb << 3;
    }
    const int rem = s1 - e;                  // 0..7 (per half-wave)
    if (rem) {
        const int last = s1 - 1;
        int ia[8];
        #pragma unroll
        for (int u = 0; u < 8; u++) ia[u] = csrc[min(e + u, last)];
        #pragma unroll
        for (int u = 0; u < 8; u++) {
            unsigned raw = ((const unsigned*)(T + (size_t)ia[u] * OD))[l32];
            raw = (u < rem) ? raw : 0u;
            union { unsigned q; __half2 h; } tt; tt.q = raw;
            float2 f = __half22float2(tt.h);
            ax += f.x; ay += f.y;
        }
    }
    float ri = r_in[v];
    f32x2 o;
    o.x = ax * ri + bc[l32 * 2];
    o.y = ay * ri + bc[l32 * 2 + 1];
    __builtin_nontemporal_store(o, (f32x2*)(out + (size_t)v * OD) + l32);
}

// ---------------- launch ----------------
extern "C" void kernel_launch(void* const* d_in, const int* in_sizes, int n_in,
                              void* d_out, int out_size, void* d_ws, size_t ws_size,
                              hipStream_t stream) {
    const float* in_feat = (const float*)d_in[0];
    const int*   src     = (const int*)d_in[1];
    const int*   dst     = (const int*)d_in[2];
    const float* W1      = (const float*)d_in[3];
    const float* b1      = (const float*)d_in[4];
    const float* W2      = (const float*)d_in[5];
    const float* b2      = (const float*)d_in[6];
    const float* Wf      = (const float*)d_in[7];
    const float* bf      = (const float*)d_in[8];
    float* out = (float*)d_out;

    const int N = in_sizes[0] / FD;        // 50000
    const int E = in_sizes[1];             // 1600000
    const int NR = (N + RN - 1) / RN;      // 196 (<= NRMAX)
    const int CS = (((E + CHUNKS - 1) / CHUNKS) + 3) & ~3;  // 4-aligned for int4

    char* ws = (char*)d_ws;
    size_t off = 0;
    auto alloc = [&](size_t bytes) -> void* {
        void* p = ws + off;
        off += (bytes + 255) / 256 * 256;
        return p;
    };
    // spack (1.6 MB) + epack (6.4 MB) adjacent; both dead before fused1 writes
    // tbuf (N*OD*2 = 6.4 MB) which aliases them.
    unsigned char* spack = (unsigned char*)alloc((size_t)E);
    int*    epack   = (int*)alloc((size_t)E * 4);
    __half* tbuf    = (__half*)spack;              // row-major [N][64]
    float*  r_out   = (float*)alloc((size_t)N * 4);
    float*  r_in    = (float*)alloc((size_t)N * 4);
    int*    hist_g  = (int*)alloc((size_t)CHUNKS * NRMAX * 4);
    int*    hist_gs = (int*)alloc((size_t)CHUNKS * NRMAX * 4);
    int*    cursor  = (int*)alloc((size_t)CHUNKS * NRMAX * 4);
    int*    scursor = (int*)alloc((size_t)CHUNKS * NRMAX * 4);
    int*    rstart  = (int*)alloc((size_t)(NR + 1) * 4);
    int*    sstart  = (int*)alloc((size_t)(NR + 1) * 4);
    int*    csrc    = (int*)alloc((size_t)E * 4);
    int*    row_start = (int*)alloc((size_t)(N + 1) * 4);
    __half* Xs      = (__half*)alloc((size_t)N * FD * 2);   // row-major [N][128]
    __half* W1t     = (__half*)alloc((size_t)FD * FD * 2);  // transposed [col][k]
    __half* Wct     = (__half*)alloc((size_t)OD * FD * 2);  // transposed [col][k]
    float*  bc      = (float*)alloc((size_t)OD * 4);
    (void)ws_size; (void)n_in; (void)out_size;

    // 6 launches total; fold spread over 16 blocks inside the scan launch.
    region_hist_kernel<<<CHUNKS, 1024, 0, stream>>>(src, dst, hist_g, hist_gs, E, NR, CS);
    scanfold_kernel<<<17, 1024, 0, stream>>>(hist_g, hist_gs, rstart, cursor, sstart, scursor,
                                             NR, E, W2, Wf, b2, bf, W1, W1t, Wct, bc);
    partition_kernel<<<CHUNKS, 1024, 0, stream>>>(src, dst, cursor, scursor, epack, spack, E, NR, CS);
    region_finish_kernel<<<NR, 1024, 0, stream>>>(epack, rstart, spack, sstart, in_feat,
                                                  csrc, row_start, r_in, r_out, Xs, N, NR, E);
    fused1_kernel<<<(N + 15) / 16, 1024, 0, stream>>>(Xs, r_in, r_out, row_start, csrc,
                                                      W1t, b1, Wct, tbuf, N);
    agg64_kernel<<<(N + 7) / 8, 256, 0, stream>>>(tbuf, r_in, row_start, csrc, bc, out, N);
}

// Round 13
// 256.736 us; speedup vs baseline: 1.0117x; 1.0030x over previous
//
#include <hip/hip_runtime.h>
#include <hip/hip_fp16.h>

#define FD 128    // hidden feature dim
#define OD 64     // output dim
#define RN 256    // nodes per region (id >> 8)
#define CHUNKS 256
#define NRMAX 1024
#define BN 64     // nodes per fused1 block (16 waves, dynamic assignment)

typedef _Float16 f16x8 __attribute__((ext_vector_type(8)));
typedef float    f32x4 __attribute__((ext_vector_type(4)));
typedef float    f32x2 __attribute__((ext_vector_type(2)));

// ---------------- pass 1: dual histograms by region (dst>>8 and src>>8) ----------------
// hist layout TRANSPOSED: hist_g[region * CHUNKS + chunk] so the scan kernel streams.
// (round-6 lesson: per-edge GLOBAL atomics cost 72us — LDS histograms + spack
// byte scatter is ~3x cheaper. Keep this structure.)

__global__ __launch_bounds__(1024) void region_hist_kernel(const int* __restrict__ src,
                                                           const int* __restrict__ dst,
                                                           int* __restrict__ hist_g,
                                                           int* __restrict__ hist_gs,
                                                           int E, int NR, int CS) {
    __shared__ int hist[NRMAX];
    __shared__ int hist_s[NRMAX];
    int c = blockIdx.x;
    for (int t = threadIdx.x; t < NR; t += 1024) { hist[t] = 0; hist_s[t] = 0; }
    __syncthreads();
    int e0 = c * CS, e1 = min(e0 + CS, E);
    int nv = (e1 - e0) & ~3;
    for (int e = e0 + threadIdx.x * 4; e < e0 + nv; e += 4096) {
        int4 d = *(const int4*)(dst + e);
        int4 s = *(const int4*)(src + e);
        atomicAdd(&hist[d.x >> 8], 1);
        atomicAdd(&hist[d.y >> 8], 1);
        atomicAdd(&hist[d.z >> 8], 1);
        atomicAdd(&hist[d.w >> 8], 1);
        atomicAdd(&hist_s[s.x >> 8], 1);
        atomicAdd(&hist_s[s.y >> 8], 1);
        atomicAdd(&hist_s[s.z >> 8], 1);
        atomicAdd(&hist_s[s.w >> 8], 1);
    }
    for (int e = e0 + nv + threadIdx.x; e < e1; e += 1024) {
        atomicAdd(&hist[dst[e] >> 8], 1);
        atomicAdd(&hist_s[src[e] >> 8], 1);
    }
    __syncthreads();
    for (int t = threadIdx.x; t < NR; t += 1024) {
        hist_g[t * CHUNKS + c]  = hist[t];
        hist_gs[t * CHUNKS + c] = hist_s[t];
    }
}

// ---------------- scan (block 0) + weight fold (blocks 1..16), one launch ----------------
// round-9 lesson: fold in ONE block = 66us latency serialization; spread one
// element per thread. Weights stored TRANSPOSED ([col][k]) so fused1's MFMA
// B-fragments are contiguous f16x8 vector loads.
__global__ __launch_bounds__(1024) void scanfold_kernel(const int* __restrict__ hist_g,
                                                        const int* __restrict__ hist_gs,
                                                        int* __restrict__ rstart,
                                                        int* __restrict__ cursor,
                                                        int* __restrict__ sstart,
                                                        int* __restrict__ scursor,
                                                        int NR, int E,
                                                        const float* __restrict__ W2,
                                                        const float* __restrict__ Wf,
                                                        const float* __restrict__ b2,
                                                        const float* __restrict__ bf,
                                                        const float* __restrict__ W1,
                                                        __half* __restrict__ W1t,
                                                        __half* __restrict__ Wct,
                                                        float* __restrict__ bc) {
    __shared__ int wsum[16];
    int tid = threadIdx.x, lane = tid & 63, w = tid >> 6;

    if (blockIdx.x >= 1) {
        // ---- fold, 1 element per thread across 16 blocks; outputs transposed ----
        int gid = (blockIdx.x - 1) * 1024 + tid;   // 0..16383
        if (gid < FD * FD) {
            int col = gid >> 7, k = gid & 127;     // W1t[col][k] = W1[k][col]
            W1t[gid] = __float2half(W1[k * FD + col]);
        }
        if (gid < FD * OD) {
            int col = gid >> 7, k = gid & 127;     // Wct[col][k] = (W2@Wf)[k][col]
            float s = 0.f;
            for (int kk = 0; kk < FD; kk++) s += W2[k * FD + kk] * Wf[kk * OD + col];
            Wct[gid] = __float2half(s);
        }
        if (gid < OD) {
            float s = bf[gid];
            for (int k = 0; k < FD; k++) s += b2[k] * Wf[k * OD + gid];
            bc[gid] = s;
        }
        return;
    }

    // ---- scan 1: dst totals ----
    int total = 0;
    if (tid < NR) {
        const int4* hp = (const int4*)(hist_g + (size_t)tid * CHUNKS);
        #pragma unroll 8
        for (int c4 = 0; c4 < CHUNKS / 4; c4++) {
            int4 h = hp[c4];
            total += h.x + h.y + h.z + h.w;
        }
    }
    int x = total;
    #pragma unroll
    for (int d = 1; d < 64; d <<= 1) {
        int t = __shfl_up(x, d, 64);
        if (lane >= d) x += t;
    }
    if (lane == 63) wsum[w] = x;
    __syncthreads();
    if (w == 0) {
        int s = (lane < 16) ? wsum[lane] : 0;
        #pragma unroll
        for (int d = 1; d < 16; d <<= 1) {
            int t = __shfl_up(s, d, 64);
            if (lane >= d) s += t;
        }
        if (lane < 16) wsum[lane] = s;
    }
    __syncthreads();
    int off = (w == 0) ? 0 : wsum[w - 1];
    if (tid < NR) {
        int start = x + off - total;
        rstart[tid] = start;
        int run = start;
        const int4* hp = (const int4*)(hist_g + (size_t)tid * CHUNKS);
        int4* cp = (int4*)(cursor + (size_t)tid * CHUNKS);
        #pragma unroll 8
        for (int c4 = 0; c4 < CHUNKS / 4; c4++) {
            int4 h = hp[c4];
            int4 o;
            o.x = run; run += h.x;
            o.y = run; run += h.y;
            o.z = run; run += h.z;
            o.w = run; run += h.w;
            cp[c4] = o;
        }
    }
    if (tid == 0) rstart[NR] = E;
    __syncthreads();
    // ---- scan 2: src totals ----
    total = 0;
    if (tid < NR) {
        const int4* hp = (const int4*)(hist_gs + (size_t)tid * CHUNKS);
        #pragma unroll 8
        for (int c4 = 0; c4 < CHUNKS / 4; c4++) {
            int4 h = hp[c4];
            total += h.x + h.y + h.z + h.w;
        }
    }
    x = total;
    #pragma unroll
    for (int d = 1; d < 64; d <<= 1) {
        int t = __shfl_up(x, d, 64);
        if (lane >= d) x += t;
    }
    if (lane == 63) wsum[w] = x;
    __syncthreads();
    if (w == 0) {
        int s = (lane < 16) ? wsum[lane] : 0;
        #pragma unroll
        for (int d = 1; d < 16; d <<= 1) {
            int t = __shfl_up(s, d, 64);
            if (lane >= d) s += t;
        }
        if (lane < 16) wsum[lane] = s;
    }
    __syncthreads();
    off = (w == 0) ? 0 : wsum[w - 1];
    if (tid < NR) {
        int start = x + off - total;
        sstart[tid] = start;
        int run = start;
        const int4* hp = (const int4*)(hist_gs + (size_t)tid * CHUNKS);
        int4* cp = (int4*)(scursor + (size_t)tid * CHUNKS);
        #pragma unroll 8
        for (int c4 = 0; c4 < CHUNKS / 4; c4++) {
            int4 h = hp[c4];
            int4 o;
            o.x = run; run += h.x;
            o.y = run; run += h.y;
            o.z = run; run += h.z;
            o.w = run; run += h.w;
            cp[c4] = o;
        }
    }
    if (tid == 0) sstart[NR] = E;
}

// dual scatter via LDS cursors: epack=((dst&255)<<17|src) by dst-region,
// spack=(src&255) bytes by src-region. NO per-edge global atomics.
__global__ __launch_bounds__(1024) void partition_kernel(const int* __restrict__ src,
                                                         const int* __restrict__ dst,
                                                         const int* __restrict__ cursor,
                                                         const int* __restrict__ scursor,
                                                         int* __restrict__ epack,
                                                         unsigned char* __restrict__ spack,
                                                         int E, int NR, int CS) {
    __shared__ int cur[NRMAX];
    __shared__ int scur[NRMAX];
    int c = blockIdx.x;
    for (int t = threadIdx.x; t < NR; t += 1024) {
        cur[t]  = cursor[(size_t)t * CHUNKS + c];
        scur[t] = scursor[(size_t)t * CHUNKS + c];
    }
    __syncthreads();
    int e0 = c * CS, e1 = min(e0 + CS, E);
    int nv = (e1 - e0) & ~3;
    for (int e = e0 + threadIdx.x * 4; e < e0 + nv; e += 4096) {
        int4 d = *(const int4*)(dst + e);
        int4 s = *(const int4*)(src + e);
        int p0 = atomicAdd(&cur[d.x >> 8], 1);
        int p1 = atomicAdd(&cur[d.y >> 8], 1);
        int p2 = atomicAdd(&cur[d.z >> 8], 1);
        int p3 = atomicAdd(&cur[d.w >> 8], 1);
        epack[p0] = ((d.x & 255) << 17) | s.x;
        epack[p1] = ((d.y & 255) << 17) | s.y;
        epack[p2] = ((d.z & 255) << 17) | s.z;
        epack[p3] = ((d.w & 255) << 17) | s.w;
        int q0 = atomicAdd(&scur[s.x >> 8], 1);
        int q1 = atomicAdd(&scur[s.y >> 8], 1);
        int q2 = atomicAdd(&scur[s.z >> 8], 1);
        int q3 = atomicAdd(&scur[s.w >> 8], 1);
        spack[q0] = (unsigned char)(s.x & 255);
        spack[q1] = (unsigned char)(s.y & 255);
        spack[q2] = (unsigned char)(s.z & 255);
        spack[q3] = (unsigned char)(s.w & 255);
    }
    for (int e = e0 + nv + threadIdx.x; e < e1; e += 1024) {
        int d = dst[e], s = src[e];
        int pos = atomicAdd(&cur[d >> 8], 1);
        epack[pos] = ((d & 255) << 17) | s;
        int qos = atomicAdd(&scur[s >> 8], 1);
        spack[qos] = (unsigned char)(s & 255);
    }
}

// ---------------- region finish: counting sort + src-degree + prescale, one launch ----------------
__global__ __launch_bounds__(1024) void region_finish_kernel(const int* __restrict__ epack,
                                                             const int* __restrict__ rstart,
                                                             const unsigned char* __restrict__ spack,
                                                             const int* __restrict__ sstart,
                                                             const float* __restrict__ in_feat,
                                                             int* __restrict__ csrc,
                                                             int* __restrict__ row_start,
                                                             float* __restrict__ r_in,
                                                             float* __restrict__ r_out,
                                                             __half* __restrict__ Xs,
                                                             int N, int NR, int E) {
    __shared__ int cnt[RN];
    __shared__ int cur[RN];
    __shared__ int wsum[16];
    __shared__ float rloc[RN];
    const int r = blockIdx.x, tid = threadIdx.x;
    const int lane = tid & 63, w = tid >> 6;

    // ---- part A: dst-region counting sort ----
    const int s0 = rstart[r], s1 = rstart[r + 1];
    if (tid < RN) cnt[tid] = 0;
    __syncthreads();
    for (int e = s0 + tid; e < s1; e += 1024)
        atomicAdd(&cnt[epack[e] >> 17], 1);
    __syncthreads();
    int cv = (tid < RN) ? cnt[tid] : 0;
    int x = cv;
    #pragma unroll
    for (int d = 1; d < 64; d <<= 1) {
        int t = __shfl_up(x, d, 64);
        if (lane >= d) x += t;
    }
    if (lane == 63 && w < 4) wsum[w] = x;
    __syncthreads();
    if (tid < RN) {
        int woff = 0;
        for (int i = 0; i < w; i++) woff += wsum[i];
        int start = s0 + x - cv + woff;
        cur[tid] = start;
        int node = r * RN + tid;
        if (node < N) {
            row_start[node] = start;
            r_in[node] = rsqrtf((float)max(cv, 1));
        }
    }
    if (r == NR - 1 && tid == 0) row_start[N] = E;
    __syncthreads();
    for (int e = s0 + tid; e < s1; e += 1024) {
        int pk = epack[e];
        int pos = atomicAdd(&cur[pk >> 17], 1);
        csrc[pos] = pk & 0x1FFFF;
    }
    __syncthreads();

    // ---- part B: src-region byte histogram -> r_out ----
    const int t0 = sstart[r], t1 = sstart[r + 1];
    if (tid < RN) cnt[tid] = 0;
    __syncthreads();
    for (int e = t0 + tid; e < t1; e += 1024)
        atomicAdd(&cnt[spack[e]], 1);
    __syncthreads();
    if (tid < RN) {
        float ro = rsqrtf((float)max(cnt[tid], 1));
        rloc[tid] = ro;
        int node = r * RN + tid;
        if (node < N) r_out[node] = ro;
    }
    __syncthreads();

    // ---- part C: prescale own 256 nodes (32 float4 per row) ----
    for (int idx = tid; idx < RN * 32; idx += 1024) {
        int nrow = idx >> 5;
        int node = r * RN + nrow;
        if (node >= N) break;
        int gi = node * 32 + (idx & 31);
        float ro = rloc[nrow];
        float4 t = ((const float4*)in_feat)[gi];
        ((__half2*)Xs)[2 * gi]     = __floats2half2_rn(t.x * ro, t.y * ro);
        ((__half2*)Xs)[2 * gi + 1] = __floats2half2_rn(t.z * ro, t.w * ro);
    }
}

// ---------------- fused layer-1 v3: 16 waves, 64 nodes, DYNAMIC work-stealing ----------------
// round-12 diagnosis: one-node-per-wave + barrier = max-of-16 Poisson degrees
// (~30% phase-A inflation; occupancy x2 changed nothing -> barrier-bound, not
// wave-count-bound). Fix: waves grab nodes from an LDS counter (fast waves
// absorb slow nodes; straggler cost -> last-node granularity ~8%). GEMM phases
// now have 32/16 tile-tasks -> ALL 16 waves work (was 8/4 idle).
__global__ __launch_bounds__(1024, 8) void fused1_kernel(const __half* __restrict__ Xs,
                                                         const float* __restrict__ r_in,
                                                         const float* __restrict__ r_out,
                                                         const int* __restrict__ rs,
                                                         const int* __restrict__ csrc,
                                                         const __half* __restrict__ W1t,
                                                         const float* __restrict__ b1,
                                                         const __half* __restrict__ Wct,
                                                         __half* __restrict__ tbuf,
                                                         int N) {
    const int tid = threadIdx.x;
    const int lane = tid & 63, w = tid >> 6;      // 16 waves
    const int l15 = lane & 15, quad = lane >> 4;
    const int base = blockIdx.x * BN;
    __shared__ __half2  zt[BN][68];    // z1 tile, row stride 272B (2-way LDS aliasing only)
    __shared__ _Float16 yt[BN][136];   // y1 tile, same stride
    __shared__ int nctr;

    if (tid == 0) nctr = 16;

    // ---- hoist GEMM1 B fragment (col tile = w&7, shared by this wave's 2 tasks) ----
    const int ct1 = w & 7;
    const int colB1 = ct1 * 16 + l15;
    f16x8 bf1[4];
    {
        const f16x8* bp = (const f16x8*)((const _Float16*)W1t + (size_t)colB1 * FD + quad * 8);
        #pragma unroll
        for (int kk = 0; kk < 4; kk++) bf1[kk] = bp[kk * 4];
    }
    __syncthreads();   // nctr visible

    // ---- phase A: dynamic node grab; wave aggregates full 128-feature row ----
    int n = w;
    while (n < BN) {
        const int v = base + n;
        float ax = 0.f, ay = 0.f;
        if (v < N) {
            int s0 = __builtin_amdgcn_readfirstlane(rs[v]);
            int s1 = __builtin_amdgcn_readfirstlane(rs[v + 1]);
            const int deg = s1 - s0;
            const int nb = deg >> 4;
            int e = s0;
            if (nb) {
                int ia[16];
                #pragma unroll
                for (int u = 0; u < 16; u++) ia[u] = csrc[e + u];
                for (int b = 1; b < nb; b++) {
                    __half2 t[16];
                    #pragma unroll
                    for (int u = 0; u < 16; u++)
                        t[u] = ((const __half2*)(Xs + (size_t)ia[u] * FD))[lane];
                    int eb = e + (b << 4);
                    #pragma unroll
                    for (int u = 0; u < 16; u++) ia[u] = csrc[eb + u];
                    #pragma unroll
                    for (int u = 0; u < 16; u++) {
                        float2 f = __half22float2(t[u]);
                        ax += f.x; ay += f.y;
                    }
                }
                __half2 t[16];
                #pragma unroll
                for (int u = 0; u < 16; u++)
                    t[u] = ((const __half2*)(Xs + (size_t)ia[u] * FD))[lane];
                #pragma unroll
                for (int u = 0; u < 16; u++) {
                    float2 f = __half22float2(t[u]);
                    ax += f.x; ay += f.y;
                }
                e += nb << 4;
            }
            const int rem = s1 - e;          // 0..15, wave-uniform
            if (rem) {
                const int last = s1 - 1;
                int ia[16];
                #pragma unroll
                for (int u = 0; u < 16; u++) ia[u] = csrc[min(e + u, last)];
                #pragma unroll
                for (int u = 0; u < 16; u++) {
                    unsigned raw = ((const unsigned*)(Xs + (size_t)ia[u] * FD))[lane];
                    raw = (u < rem) ? raw : 0u;
                    union { unsigned q; __half2 h; } tt; tt.q = raw;
                    float2 f = __half22float2(tt.h);
                    ax += f.x; ay += f.y;
                }
            }
            float ri = r_in[v];
            zt[n][lane] = __floats2half2_rn(ax * ri, ay * ri);
        } else {
            zt[n][lane] = __floats2half2_rn(0.f, 0.f);
        }
        int nn;
        if (lane == 0) nn = atomicAdd(&nctr, 1);
        n = __shfl(nn, 0);
    }
    __syncthreads();

    // ---- phase B: GEMM1 -> yt ; 32 tile-tasks (4 row-tiles x 8 col-tiles), 2 per wave ----
    #pragma unroll
    for (int t2 = 0; t2 < 2; t2++) {
        const int t = w + 16 * t2;             // rt = t>>3 in {0..3}, ct = w&7 (same both)
        const int rt = t >> 3;
        const int r0 = rt * 16;
        const _Float16* Arow = (const _Float16*)&zt[r0 + l15][0] + quad * 8;
        f16x8 afrag[4];
        #pragma unroll
        for (int kk = 0; kk < 4; kk++) afrag[kk] = *(const f16x8*)(Arow + kk * 32);
        f32x4 acc = {0.f, 0.f, 0.f, 0.f};
        #pragma unroll
        for (int kk = 0; kk < 4; kk++)
            acc = __builtin_amdgcn_mfma_f32_16x16x32_f16(afrag[kk], bf1[kk], acc, 0, 0, 0);
        float bb = b1[colB1];
        #pragma unroll
        for (int r = 0; r < 4; r++) {
            int row = r0 + quad * 4 + r;
            int v = base + row;
            float rsc = (v < N) ? r_out[v] : 0.f;
            yt[row][colB1] = (_Float16)(fmaxf(acc[r] + bb, 0.f) * rsc);
        }
    }
    __syncthreads();

    // ---- phase C: GEMM2 -> tbuf ; 16 tile-tasks (4x4), 1 per wave ----
    {
        const int rt = w >> 2, ct = w & 3;
        const int colB2 = ct * 16 + l15;
        const f16x8* bp = (const f16x8*)((const _Float16*)Wct + (size_t)colB2 * FD + quad * 8);
        f16x8 bf2[4];
        #pragma unroll
        for (int kk = 0; kk < 4; kk++) bf2[kk] = bp[kk * 4];
        const int r0 = rt * 16;
        const _Float16* Arow = &yt[r0 + l15][0] + quad * 8;
        f16x8 afrag[4];
        #pragma unroll
        for (int kk = 0; kk < 4; kk++) afrag[kk] = *(const f16x8*)(Arow + kk * 32);
        f32x4 acc = {0.f, 0.f, 0.f, 0.f};
        #pragma unroll
        for (int kk = 0; kk < 4; kk++)
            acc = __builtin_amdgcn_mfma_f32_16x16x32_f16(afrag[kk], bf2[kk], acc, 0, 0, 0);
        #pragma unroll
        for (int r = 0; r < 4; r++) {
            int row = r0 + quad * 4 + r;
            int v = base + row;
            if (v < N)
                tbuf[(size_t)v * OD + colB2] = __float2half(acc[r]);
        }
    }
}

// ---------------- final aggregation: 2 nodes per wave, pipelined ----------------
__global__ __launch_bounds__(256) void agg64_kernel(const __half* __restrict__ T,
                                                    const float* __restrict__ r_in,
                                                    const int* __restrict__ rs,
                                                    const int* __restrict__ csrc,
                                                    const float* __restrict__ bc,
                                                    float* __restrict__ out, int N) {
    const int tid = threadIdx.x;
    const int lane = tid & 63, wv = tid >> 6;
    const int hf = lane >> 5, l32 = lane & 31;
    int v = blockIdx.x * 8 + wv * 2 + hf;
    if (v >= N) return;
    int s0 = rs[v], s1 = rs[v + 1];          // half-wave uniform
    const int deg = s1 - s0;
    float ax = 0.f, ay = 0.f;
    const int nb = deg >> 3;
    int e = s0;
    if (nb) {
        int ia[8];
        #pragma unroll
        for (int u = 0; u < 8; u++) ia[u] = csrc[e + u];
        for (int b = 1; b < nb; b++) {
            __half2 t[8];
            #pragma unroll
            for (int u = 0; u < 8; u++)
                t[u] = ((const __half2*)(T + (size_t)ia[u] * OD))[l32];
            int eb = e + (b << 3);
            #pragma unroll
            for (int u = 0; u < 8; u++) ia[u] = csrc[eb + u];
            #pragma unroll
            for (int u = 0; u < 8; u++) {
                float2 f = __half22float2(t[u]);
                ax += f.x; ay += f.y;
            }
        }
        __half2 t[8];
        #pragma unroll
        for (int u = 0; u < 8; u++)
            t[u] = ((const __half2*)(T + (size_t)ia[u] * OD))[l32];
        #pragma unroll
        for (int u = 0; u < 8; u++) {
            float2 f = __half22float2(t[u]);
            ax += f.x; ay += f.y;
        }
        e += nb << 3;
    }
    const int rem = s1 - e;                  // 0..7 (per half-wave)
    if (rem) {
        const int last = s1 - 1;
        int ia[8];
        #pragma unroll
        for (int u = 0; u < 8; u++) ia[u] = csrc[min(e + u, last)];
        #pragma unroll
        for (int u = 0; u < 8; u++) {
            unsigned raw = ((const unsigned*)(T + (size_t)ia[u] * OD))[l32];
            raw = (u < rem) ? raw : 0u;
            union { unsigned q; __half2 h; } tt; tt.q = raw;
            float2 f = __half22float2(tt.h);
            ax += f.x; ay += f.y;
        }
    }
    float ri = r_in[v];
    f32x2 o;
    o.x = ax * ri + bc[l32 * 2];
    o.y = ay * ri + bc[l32 * 2 + 1];
    __builtin_nontemporal_store(o, (f32x2*)(out + (size_t)v * OD) + l32);
}

// ---------------- launch ----------------
extern "C" void kernel_launch(void* const* d_in, const int* in_sizes, int n_in,
                              void* d_out, int out_size, void* d_ws, size_t ws_size,
                              hipStream_t stream) {
    const float* in_feat = (const float*)d_in[0];
    const int*   src     = (const int*)d_in[1];
    const int*   dst     = (const int*)d_in[2];
    const float* W1      = (const float*)d_in[3];
    const float* b1      = (const float*)d_in[4];
    const float* W2      = (const float*)d_in[5];
    const float* b2      = (const float*)d_in[6];
    const float* Wf      = (const float*)d_in[7];
    const float* bf      = (const float*)d_in[8];
    float* out = (float*)d_out;

    const int N = in_sizes[0] / FD;        // 50000
    const int E = in_sizes[1];             // 1600000
    const int NR = (N + RN - 1) / RN;      // 196 (<= NRMAX)
    const int CS = (((E + CHUNKS - 1) / CHUNKS) + 3) & ~3;  // 4-aligned for int4

    char* ws = (char*)d_ws;
    size_t off = 0;
    auto alloc = [&](size_t bytes) -> void* {
        void* p = ws + off;
        off += (bytes + 255) / 256 * 256;
        return p;
    };
    // spack (1.6 MB) + epack (6.4 MB) adjacent; both dead before fused1 writes
    // tbuf (N*OD*2 = 6.4 MB) which aliases them.
    unsigned char* spack = (unsigned char*)alloc((size_t)E);
    int*    epack   = (int*)alloc((size_t)E * 4);
    __half* tbuf    = (__half*)spack;              // row-major [N][64]
    float*  r_out   = (float*)alloc((size_t)N * 4);
    float*  r_in    = (float*)alloc((size_t)N * 4);
    int*    hist_g  = (int*)alloc((size_t)CHUNKS * NRMAX * 4);
    int*    hist_gs = (int*)alloc((size_t)CHUNKS * NRMAX * 4);
    int*    cursor  = (int*)alloc((size_t)CHUNKS * NRMAX * 4);
    int*    scursor = (int*)alloc((size_t)CHUNKS * NRMAX * 4);
    int*    rstart  = (int*)alloc((size_t)(NR + 1) * 4);
    int*    sstart  = (int*)alloc((size_t)(NR + 1) * 4);
    int*    csrc    = (int*)alloc((size_t)E * 4);
    int*    row_start = (int*)alloc((size_t)(N + 1) * 4);
    __half* Xs      = (__half*)alloc((size_t)N * FD * 2);   // row-major [N][128]
    __half* W1t     = (__half*)alloc((size_t)FD * FD * 2);  // transposed [col][k]
    __half* Wct     = (__half*)alloc((size_t)OD * FD * 2);  // transposed [col][k]
    float*  bc      = (float*)alloc((size_t)OD * 4);
    (void)ws_size; (void)n_in; (void)out_size;

    // 6 launches total; fold spread over 16 blocks inside the scan launch.
    region_hist_kernel<<<CHUNKS, 1024, 0, stream>>>(src, dst, hist_g, hist_gs, E, NR, CS);
    scanfold_kernel<<<17, 1024, 0, stream>>>(hist_g, hist_gs, rstart, cursor, sstart, scursor,
                                             NR, E, W2, Wf, b2, bf, W1, W1t, Wct, bc);
    partition_kernel<<<CHUNKS, 1024, 0, stream>>>(src, dst, cursor, scursor, epack, spack, E, NR, CS);
    region_finish_kernel<<<NR, 1024, 0, stream>>>(epack, rstart, spack, sstart, in_feat,
                                                  csrc, row_start, r_in, r_out, Xs, N, NR, E);
    fused1_kernel<<<(N + BN - 1) / BN, 1024, 0, stream>>>(Xs, r_in, r_out, row_start, csrc,
                                                          W1t, b1, Wct, tbuf, N);
    agg64_kernel<<<(N + 7) / 8, 256, 0, stream>>>(tbuf, r_in, row_start, csrc, bc, out, N);
}